// Round 7
// baseline (283.734 us; speedup 1.0000x reference)
//
#include <hip/hip_runtime.h>

// CapsClass2d dynamic routing — MFMA 16x16x16, max-TLP simple loop.
// b=256, P=1152, C=10, os=is=16, 3 iterations.
//
// R6 post-mortem: cooperative fusion failed correctness (grid-sync/coherence
// under graph capture) — withdrawn. Back to the verified multi-dispatch
// skeleton (R5 math, absmax 0.0059).
// R5 facts: GLL pipeline is a pessimization (77us vs R2's 61us plain loads);
// occupancy measured 10.4% (~3.3 waves/CU) -> latency-bound with no TLP.
// This round: maximize resident waves, simplest loop.
//   - No GLL/staging: LDS = merge (10.3KB) + vsum tile (10.5KB) = 20.8KB.
//   - VGPR < 128 (-> 4 waves/SIMD): vs in LDS (was 40 VGPR); acc[10] (40
//     VGPR) eliminated by RECOMPUTING the MFMA after softmax
//     (sacc += coup * mfma(af,b)) — MFMA util is 1.5%, 2x MFMA is free.
//   - af[10]+bfrag batched per position (11 coalesced 512B wave-loads).
//   - Grid 768 (XCD-swizzled), 3 blocks/CU -> 12 waves/CU resident.
//
// MFMA 16x16x16 (K=16 exact): all 64 lanes carry data (8B/lane frags).
//   A[m=o][k=i]: m=lane&15, k=(lane>>4)*4+j
//   B[k=i][n=b]: n=lane&15, k=(lane>>4)*4+j
//   C/D: col(b)=lane&15, row(o)=(lane>>4)*4+reg
// Wave = 16 batches x 10 c x PW=6 positions; block = 4 waves same b-tile.
// Merge: LDS -> part[slice][b][j]; squash reduces 48 partials.

#define NPOS 1152
#define NC 10
#define OS 16
#define IS 16
#define NB 256
#define CO (NC * OS)            // 160
#define CAPS_EPS 1e-8f
#define PW 6                    // positions per wave
#define PBLK (NPOS / (4 * PW))  // 48 p-slices
#define PPB (4 * PW)            // 24 positions per slice
#define NA2 (NPOS * NC * 64)    // A uint2 slots (737280, 5.9 MB)
#define NB2 (16 * NPOS * 64)    // B uint2 slots (1179648, 9.4 MB)
#define VSLD 164                // vs_lds row stride (floats): 16B-aligned, 2-way banks

typedef __attribute__((ext_vector_type(4))) short bf16x4;
typedef __attribute__((ext_vector_type(4))) _Float16 halfx4;
typedef __attribute__((ext_vector_type(4))) float floatx4;

#if __has_builtin(__builtin_amdgcn_mfma_f32_16x16x16bf16_1k)
  #define MFMA_KIND 1
#elif __has_builtin(__builtin_amdgcn_mfma_f32_16x16x16f16)
  #define MFMA_KIND 0
#else
  #define MFMA_KIND 2            // host pass: stub
#endif

__device__ __forceinline__ unsigned f2bf_rne(float x) {
    union { float f; unsigned u; } v; v.f = x;
    return (v.u + 0x7FFFu + ((v.u >> 16) & 1u)) >> 16;
}

__device__ __forceinline__ uint2 pack4(float4 f) {
#if MFMA_KIND != 0
    uint2 r;
    r.x = f2bf_rne(f.x) | (f2bf_rne(f.y) << 16);
    r.y = f2bf_rne(f.z) | (f2bf_rne(f.w) << 16);
    return r;
#else
    union { uint2 u; halfx4 v; } r;
    r.v[0] = (_Float16)f.x; r.v[1] = (_Float16)f.y;
    r.v[2] = (_Float16)f.z; r.v[3] = (_Float16)f.w;
    return r.u;
#endif
}

__device__ __forceinline__ floatx4 MFMA16(uint2 a, uint2 b, floatx4 c) {
#if MFMA_KIND == 1
    union { uint2 u; bf16x4 v; } A, B; A.u = a; B.u = b;
    return __builtin_amdgcn_mfma_f32_16x16x16bf16_1k(A.v, B.v, c, 0, 0, 0);
#elif MFMA_KIND == 0
    union { uint2 u; halfx4 v; } A, B; A.u = a; B.u = b;
    return __builtin_amdgcn_mfma_f32_16x16x16f16(A.v, B.v, c, 0, 0, 0);
#else
    (void)a; (void)b;
    return c;   // host pass stub — never executed
#endif
}

// Pre-convert W and poses into 16x16x16 fragment-layout buffers (8B/lane/frag).
// wsA slot (p*10+c)*64+L : W[p][c][o=L&15][i=(L>>4)*4 ..+3]
// wsB slot (bt*1152+p)*64+L : X[bt*16+(L&15)][p][(L>>4)*4 ..+3]   (bt-major)
__global__ __launch_bounds__(256) void preconv2_kernel(
    const float* __restrict__ poses, const float* __restrict__ weight,
    uint2* __restrict__ wsA, uint2* __restrict__ wsB)
{
    const int gid = blockIdx.x * 256 + threadIdx.x;
    if (gid < NA2) {
        const int L = gid & 63, pc = gid >> 6;
        const float4 src = *(const float4*)(weight + (size_t)pc * 256 + (L & 15) * 16 + (L >> 4) * 4);
        wsA[gid] = pack4(src);
    } else {
        const int s = gid - NA2;
        if (s < NB2) {
            const int L = s & 63, bp = s >> 6;
            const int p = bp % NPOS, bt = bp / NPOS;
            const float4 src = *(const float4*)(poses +
                ((size_t)(bt * 16 + (L & 15)) * NPOS + p) * IS + (L >> 4) * 4);
            wsB[s] = pack4(src);
        }
    }
}

template <int IT>
__global__ __launch_bounds__(256) void caps_votes4(
    const uint2* __restrict__ wsA, const uint2* __restrict__ wsB,
    const float* __restrict__ vsum, float* __restrict__ part,
    float* __restrict__ out_coup)
{
    const int t    = threadIdx.x;
    const int wave = t >> 6, lane = t & 63;
    const int bcol = lane & 15, quad = lane >> 4;

    // XCD-aware decode: consecutive ids round-robin 8 XCDs; each XCD owns 6
    // whole slices; the 16 b-tile sharers of a slice are adjacent (spacing 8).
    const int n    = blockIdx.x;                 // 0..767
    const int xcd  = n & 7, j = n >> 3;          // j: 0..95
    const int slice = xcd * (PBLK / 8) + (j >> 4);  // 0..47
    const int bt   = j & 15;
    const int b0   = bt * 16;
    const int pbase = slice * PPB + wave * PW;

    __shared__ float s_lds[16 * 161];                       // merge (+1 pad)
    __shared__ float vs_lds[(IT > 0) ? 16 * VSLD : 4];      // vsum tile

    for (int k = t; k < 16 * 161; k += 256) s_lds[k] = 0.f;
    if (IT > 0) {
        for (int k = t; k < 16 * CO; k += 256) {
            const int b = k / CO, j2 = k - b * CO;
            vs_lds[b * VSLD + j2] = vsum[(size_t)(b0 + b) * CO + j2];
        }
    }
    __syncthreads();

    floatx4 sacc[NC];
#pragma unroll
    for (int c = 0; c < NC; ++c) sacc[c] = (floatx4)(0.f);

    for (int pi = 0; pi < PW; ++pi) {
        const int p = pbase + pi;
        const uint2* ap = wsA + ((size_t)p * NC) * 64 + lane;
        const uint2 bfrag = wsB[((size_t)bt * NPOS + p) * 64 + lane];

        uint2 af[NC];
#pragma unroll
        for (int c = 0; c < NC; ++c) af[c] = ap[(size_t)c * 64];

        if (IT == 0) {
#pragma unroll
            for (int c = 0; c < NC; ++c) sacc[c] = MFMA16(af[c], bfrag, sacc[c]);
        } else {
            // pass 1: logits (MFMA result consumed immediately; acc[] never stored)
            float lg[NC];
            float mx = -1e30f;
#pragma unroll
            for (int c = 0; c < NC; ++c) {
                const floatx4 tmp = MFMA16(af[c], bfrag, (floatx4)(0.f));
                const float4 vsc = *(const float4*)(vs_lds + bcol * VSLD + c * 16 + quad * 4);
                float pt = vsc.x * tmp[0] + vsc.y * tmp[1]
                         + vsc.z * tmp[2] + vsc.w * tmp[3];
                pt += __shfl_xor(pt, 16);
                pt += __shfl_xor(pt, 32);
                lg[c] = pt;
                mx = fmaxf(mx, pt);
            }
            float coup[NC];
            float sum = 0.f;
#pragma unroll
            for (int c = 0; c < NC; ++c) { coup[c] = __expf(lg[c] - mx); sum += coup[c]; }
            const float inv = 1.f / sum;
#pragma unroll
            for (int c = 0; c < NC; ++c) coup[c] *= inv;

            if (IT == 2 && quad == 0) {
                // p innermost out_coup dim -> L2 write-back coalesces
                float* cp = out_coup + (size_t)(b0 + bcol) * (NC * NPOS) + p;
#pragma unroll
                for (int c = 0; c < NC; ++c) cp[c * NPOS] = coup[c];
            }

            // pass 2: recompute MFMA (bit-identical), weighted accumulate
#pragma unroll
            for (int c = 0; c < NC; ++c) {
                const floatx4 tmp = MFMA16(af[c], bfrag, (floatx4)(0.f));
#pragma unroll
                for (int r = 0; r < 4; ++r) sacc[c][r] += coup[c] * tmp[r];
            }
        }
    }

    // merge the block's 4 waves in LDS, then coalesced partial store
    const float scale = (IT == 0) ? 0.1f : 1.f;
#pragma unroll
    for (int c = 0; c < NC; ++c)
#pragma unroll
        for (int r = 0; r < 4; ++r)
            atomicAdd(&s_lds[bcol * 161 + c * 16 + quad * 4 + r], scale * sacc[c][r]);
    __syncthreads();

    float* pp = part + ((size_t)slice * NB + b0) * CO;
    for (int k = t; k < 16 * CO; k += 256) {
        const int b = k / CO, jj = k - b * CO;
        pp[(size_t)b * CO + jj] = s_lds[b * 161 + jj];
    }
}

// Fallback (tiny ws): direct float4 loads + in-register conversion, atomic merge.
__global__ __launch_bounds__(256) void caps_votes_fb(
    const float* __restrict__ poses, const float* __restrict__ weight,
    const float* __restrict__ vsum, float* __restrict__ sbuf,
    float* __restrict__ out_coup, int it)
{
    const int t = threadIdx.x, wave = t >> 6, lane = t & 63;
    const int bcol = lane & 15, quad = lane >> 4;
    const int bt = blockIdx.y, b0 = bt * 16;
    const int pbase = blockIdx.x * PPB + wave * PW;

    __shared__ float s_lds[16 * 161];
    for (int k = t; k < 16 * 161; k += 256) s_lds[k] = 0.f;

    float4 vs[NC];
    if (it > 0) {
        const float* vp = vsum + (size_t)(b0 + bcol) * CO + quad * 4;
#pragma unroll
        for (int c = 0; c < NC; ++c) vs[c] = *(const float4*)(vp + c * 16);
    }
    __syncthreads();

    floatx4 sacc[NC];
#pragma unroll
    for (int c = 0; c < NC; ++c) sacc[c] = (floatx4)(0.f);

    for (int pi = 0; pi < PW; ++pi) {
        const int p = pbase + pi;
        const uint2 bfrag = pack4(*(const float4*)(poses +
            ((size_t)(b0 + bcol) * NPOS + p) * IS + quad * 4));
        floatx4 acc[NC];
#pragma unroll
        for (int c = 0; c < NC; ++c) {
            const uint2 a = pack4(*(const float4*)(weight +
                (size_t)(p * NC + c) * 256 + bcol * 16 + quad * 4));
            acc[c] = MFMA16(a, bfrag, (floatx4)(0.f));
        }
        if (it == 0) {
#pragma unroll
            for (int c = 0; c < NC; ++c)
#pragma unroll
                for (int r = 0; r < 4; ++r) sacc[c][r] += acc[c][r];
        } else {
            float lg[NC], mx = -1e30f;
#pragma unroll
            for (int c = 0; c < NC; ++c) {
                float pt = vs[c].x * acc[c][0] + vs[c].y * acc[c][1]
                         + vs[c].z * acc[c][2] + vs[c].w * acc[c][3];
                pt += __shfl_xor(pt, 16);
                pt += __shfl_xor(pt, 32);
                lg[c] = pt; mx = fmaxf(mx, pt);
            }
            float coup[NC], sum = 0.f;
#pragma unroll
            for (int c = 0; c < NC; ++c) { coup[c] = __expf(lg[c] - mx); sum += coup[c]; }
            const float inv = 1.f / sum;
#pragma unroll
            for (int c = 0; c < NC; ++c) coup[c] *= inv;
            if (it == 2 && quad == 0) {
                float* cp = out_coup + (size_t)(b0 + bcol) * (NC * NPOS) + p;
#pragma unroll
                for (int c = 0; c < NC; ++c) cp[c * NPOS] = coup[c];
            }
#pragma unroll
            for (int c = 0; c < NC; ++c)
#pragma unroll
                for (int r = 0; r < 4; ++r) sacc[c][r] += coup[c] * acc[c][r];
        }
    }

    const float scale = (it == 0) ? 0.1f : 1.f;
#pragma unroll
    for (int c = 0; c < NC; ++c)
#pragma unroll
        for (int r = 0; r < 4; ++r)
            atomicAdd(&s_lds[bcol * 161 + c * 16 + quad * 4 + r], scale * sacc[c][r]);
    __syncthreads();
    for (int k = t; k < 16 * CO; k += 256) {
        const int b = k / CO, jj = k - b * CO;
        unsafeAtomicAdd(&sbuf[(size_t)(b0 + b) * CO + jj], s_lds[b * 161 + jj]);
    }
}

__global__ __launch_bounds__(256) void caps_squash_kernel(
    const float* __restrict__ rbias,   // [10, 16]
    float* __restrict__ sbuf,          // npart>0: part[npart][256][160]; else [256][160]
    float* __restrict__ vsum,          // [256, 10, 16]
    float* __restrict__ out_poses,     // [256, 10, 16]
    float* __restrict__ out_act,       // [256, 10]
    int it, int npart)
{
    const int b = blockIdx.x;
    const int t = threadIdx.x;
    if (t >= CO) return;
    const int c = t >> 4;

    const size_t idx = (size_t)b * CO + t;
    float s;
    if (npart > 0) {
        const float* p = sbuf + idx;
        const size_t stride = (size_t)NB * CO;
        float a0 = 0.f, a1 = 0.f, a2 = 0.f, a3 = 0.f;
        int px = 0;
        for (; px + 4 <= npart; px += 4) {
            a0 += p[(size_t)(px + 0) * stride];
            a1 += p[(size_t)(px + 1) * stride];
            a2 += p[(size_t)(px + 2) * stride];
            a3 += p[(size_t)(px + 3) * stride];
        }
        for (; px < npart; ++px) a0 += p[(size_t)px * stride];
        s = ((a0 + a1) + (a2 + a3)) + rbias[t];
    } else {
        s = sbuf[idx] + rbias[t];
    }

    float sq = s * s;
    sq += __shfl_xor(sq, 1);
    sq += __shfl_xor(sq, 2);
    sq += __shfl_xor(sq, 4);
    sq += __shfl_xor(sq, 8);
    const float f = (sq / (1.f + sq)) * rsqrtf(sq + CAPS_EPS);
    const float v = f * s;

    if (it < 2) {
        vsum[idx] += v;
        if (npart == 0) sbuf[idx] = 0.f;   // re-arm accumulator (legacy path)
    } else {
        out_poses[idx] = v;
        if ((t & 15) == 0) out_act[(size_t)b * NC + c] = sqrtf(f * f * sq + CAPS_EPS);
    }
}

extern "C" void kernel_launch(void* const* d_in, const int* in_sizes, int n_in,
                              void* d_out, int out_size, void* d_ws, size_t ws_size,
                              hipStream_t stream) {
    const float* poses  = (const float*)d_in[0];
    // d_in[1] (input_caps_activations) unused by the reference computation.
    const float* weight = (const float*)d_in[2];
    const float* rbias  = (const float*)d_in[3];

    float* out       = (float*)d_out;
    float* out_poses = out;                                   // 256*10*16
    float* out_act   = out + (size_t)NB * CO;                 // 256*10
    float* out_coup  = out_act + (size_t)NB * NC;             // 256*10*1152

    const size_t part_bytes = (size_t)PBLK * NB * CO * sizeof(float);  // 7.86 MB
    const size_t vsum_bytes = (size_t)NB * CO * sizeof(float);         // 160 KB
    const size_t frag_bytes = (size_t)(NA2 + NB2) * sizeof(uint2);     // 15.3 MB
    const size_t need_full  = part_bytes + vsum_bytes + frag_bytes;    // 23.4 MB

    if (ws_size >= need_full) {
        float* part = (float*)d_ws;
        float* vsum = part + (size_t)PBLK * NB * CO;
        uint2* wsA  = (uint2*)((char*)d_ws + part_bytes + vsum_bytes);
        uint2* wsB  = wsA + NA2;

        (void)hipMemsetAsync(vsum, 0, vsum_bytes, stream);
        hipLaunchKernelGGL(preconv2_kernel,
                           dim3((NA2 + NB2) / 256), dim3(256), 0, stream,
                           poses, weight, wsA, wsB);

        hipLaunchKernelGGL((caps_votes4<0>), dim3(PBLK * 16), dim3(256), 0, stream,
                           wsA, wsB, vsum, part, out_coup);
        hipLaunchKernelGGL(caps_squash_kernel, dim3(NB), dim3(256), 0, stream,
                           rbias, part, vsum, out_poses, out_act, 0, PBLK);
        hipLaunchKernelGGL((caps_votes4<1>), dim3(PBLK * 16), dim3(256), 0, stream,
                           wsA, wsB, vsum, part, out_coup);
        hipLaunchKernelGGL(caps_squash_kernel, dim3(NB), dim3(256), 0, stream,
                           rbias, part, vsum, out_poses, out_act, 1, PBLK);
        hipLaunchKernelGGL((caps_votes4<2>), dim3(PBLK * 16), dim3(256), 0, stream,
                           wsA, wsB, vsum, part, out_coup);
        hipLaunchKernelGGL(caps_squash_kernel, dim3(NB), dim3(256), 0, stream,
                           rbias, part, vsum, out_poses, out_act, 2, PBLK);
    } else {
        // legacy small-ws path: atomic accumulator, multi-dispatch
        float* sbuf = (float*)d_ws;
        float* vsum = sbuf + (size_t)NB * CO;
        (void)hipMemsetAsync(d_ws, 0, 2 * vsum_bytes, stream);
        for (int it = 0; it < 3; ++it) {
            hipLaunchKernelGGL(caps_votes_fb, dim3(PBLK, 16), dim3(256), 0, stream,
                               poses, weight, vsum, sbuf, out_coup, it);
            hipLaunchKernelGGL(caps_squash_kernel, dim3(NB), dim3(256), 0, stream,
                               rbias, sbuf, vsum, out_poses, out_act, it, 0);
        }
    }
}

// Round 8
// 271.009 us; speedup vs baseline: 1.0470x; 1.0470x over previous
//
#include <hip/hip_runtime.h>

// CapsClass2d dynamic routing — materialize votes (bf16), stream iterations.
// b=256, P=1152, C=10, os=is=16, 3 iterations.
//
// R7 post-mortem: 7-round invariant — any per-(p,c) frag-read MFMA kernel
// costs 60-85us regardless of structure (plus a 40ms fully-serialized-miss
// anomaly under rocprof). Stop rearranging loads; change the dataflow:
//   K1 caps_mat: MFMA votes from RAW inputs (verified frag math, no preconv),
//     accumulate it0 s -> part (proven merge path), AND store votes bf16
//     [b][c][p][o] (94MB) to ws.
//   K2 caps_route<it>: block=b, 512 thr. Pass1: thread<->p, coalesced 32B/lane
//     vote-row reads, in-thread softmax (no shuffles), coup->LDS. Pass2:
//     thread<->(c,o,seg) reduces sum_p coup*votes (L2-resident re-read).
//     s complete per-block -> squash fused in tail (vsum / final outputs).
//   No MFMA, no part, no separate squash for it>=1. K2 duration directly
//   measures ws streaming BW (diagnostic for the serialized-miss mystery).
//
// MFMA 16x16x16 (K=16 exact), verified layouts:
//   A[m=o][k=i]: m=lane&15, k=(lane>>4)*4+j
//   B[k=i][n=b]: n=lane&15, k=(lane>>4)*4+j
//   C/D: col(b)=lane&15, row(o)=(lane>>4)*4+reg

#define NPOS 1152
#define NC 10
#define OS 16
#define IS 16
#define NB 256
#define CO (NC * OS)            // 160
#define CAPS_EPS 1e-8f
#define PW 6                    // positions per wave (K1)
#define PBLK (NPOS / (4 * PW))  // 48 p-slices
#define PPB (4 * PW)            // 24 positions per slice

typedef __attribute__((ext_vector_type(4))) short bf16x4;
typedef __attribute__((ext_vector_type(4))) _Float16 halfx4;
typedef __attribute__((ext_vector_type(4))) float floatx4;

#if __has_builtin(__builtin_amdgcn_mfma_f32_16x16x16bf16_1k)
  #define MFMA_KIND 1
#elif __has_builtin(__builtin_amdgcn_mfma_f32_16x16x16f16)
  #define MFMA_KIND 0
#else
  #define MFMA_KIND 2            // host pass: stub
#endif

__device__ __forceinline__ unsigned f2bf_rne(float x) {
    union { float f; unsigned u; } v; v.f = x;
    return (v.u + 0x7FFFu + ((v.u >> 16) & 1u)) >> 16;
}

__device__ __forceinline__ uint2 pack4(float4 f) {
#if MFMA_KIND != 0
    uint2 r;
    r.x = f2bf_rne(f.x) | (f2bf_rne(f.y) << 16);
    r.y = f2bf_rne(f.z) | (f2bf_rne(f.w) << 16);
    return r;
#else
    union { uint2 u; halfx4 v; } r;
    r.v[0] = (_Float16)f.x; r.v[1] = (_Float16)f.y;
    r.v[2] = (_Float16)f.z; r.v[3] = (_Float16)f.w;
    return r.u;
#endif
}

__device__ __forceinline__ floatx4 MFMA16(uint2 a, uint2 b, floatx4 c) {
#if MFMA_KIND == 1
    union { uint2 u; bf16x4 v; } A, B; A.u = a; B.u = b;
    return __builtin_amdgcn_mfma_f32_16x16x16bf16_1k(A.v, B.v, c, 0, 0, 0);
#elif MFMA_KIND == 0
    union { uint2 u; halfx4 v; } A, B; A.u = a; B.u = b;
    return __builtin_amdgcn_mfma_f32_16x16x16f16(A.v, B.v, c, 0, 0, 0);
#else
    (void)a; (void)b;
    return c;   // host pass stub — never executed
#endif
}

// bf16 (stored as u16) -> f32
__device__ __forceinline__ float bflo(unsigned u) {
    union { unsigned x; float f; } v; v.x = u << 16; return v.f;
}
__device__ __forceinline__ float bfhi(unsigned u) {
    union { unsigned x; float f; } v; v.x = u & 0xffff0000u; return v.f;
}
__device__ __forceinline__ float bfu(unsigned short u) {
    union { unsigned x; float f; } v; v.x = ((unsigned)u) << 16; return v.f;
}

// ================= K1: votes materialization + it0 accumulation =============
// Reads RAW poses/weight (d_in — the fast-path memory per preconv evidence),
// stores votes[b][c][p][o] bf16 to ws, merges it0 s into part[slice][b][j].
__global__ __launch_bounds__(256) void caps_mat(
    const float* __restrict__ poses, const float* __restrict__ weight,
    unsigned short* __restrict__ votes, float* __restrict__ part)
{
    const int t    = threadIdx.x;
    const int wave = t >> 6, lane = t & 63;
    const int bcol = lane & 15, quad = lane >> 4;

    // XCD-aware decode (R5/R7-tested): each XCD owns 6 whole slices.
    const int n     = blockIdx.x;                   // 0..767
    const int xcd   = n & 7, j = n >> 3;            // j: 0..95
    const int slice = xcd * (PBLK / 8) + (j >> 4);  // 0..47
    const int bt    = j & 15;
    const int b0    = bt * 16;
    const int pbase = slice * PPB + wave * PW;

    __shared__ float s_lds[16 * 161];               // merge (+1 pad)
    for (int k = t; k < 16 * 161; k += 256) s_lds[k] = 0.f;
    __syncthreads();

    floatx4 sacc[NC];
#pragma unroll
    for (int c = 0; c < NC; ++c) sacc[c] = (floatx4)(0.f);

    for (int pi = 0; pi < PW; ++pi) {
        const int p = pbase + pi;
        const uint2 bfrag = pack4(*(const float4*)(poses +
            ((size_t)(b0 + bcol) * NPOS + p) * IS + quad * 4));

        float4 ar[NC];
#pragma unroll
        for (int c = 0; c < NC; ++c)
            ar[c] = *(const float4*)(weight +
                ((size_t)p * NC + c) * 256 + bcol * 16 + quad * 4);

#pragma unroll
        for (int c = 0; c < NC; ++c) {
            const uint2 af = pack4(ar[c]);
            const floatx4 tmp = MFMA16(af, bfrag, (floatx4)(0.f));
            // store vote row fragment: [b0+bcol][c][p][quad*4 .. +3]
            const size_t vidx = (((size_t)(b0 + bcol) * NC + c) * NPOS + p) * 16 + quad * 4;
            float4 tf; tf.x = tmp[0]; tf.y = tmp[1]; tf.z = tmp[2]; tf.w = tmp[3];
            *(uint2*)(votes + vidx) = pack4(tf);
            sacc[c] = sacc[c] + tmp;
        }
    }

    // merge the block's 4 waves in LDS, then coalesced partial store (x0.1)
#pragma unroll
    for (int c = 0; c < NC; ++c)
#pragma unroll
        for (int r = 0; r < 4; ++r)
            atomicAdd(&s_lds[bcol * 161 + c * 16 + quad * 4 + r], 0.1f * sacc[c][r]);
    __syncthreads();

    float* pp = part + ((size_t)slice * NB + b0) * CO;
    for (int k = t; k < 16 * CO; k += 256) {
        const int b = k / CO, jj = k - b * CO;
        pp[(size_t)b * CO + jj] = s_lds[b * 161 + jj];
    }
}

// ================= K2: routing iteration, pure streaming ====================
// Block = one batch b (grid 256), 512 threads.
template <int ITX>
__global__ __launch_bounds__(512) void caps_route(
    const unsigned short* __restrict__ votes,
    const float* __restrict__ rbias,
    float* __restrict__ vsum,
    float* __restrict__ out_coup,
    float* __restrict__ out_poses,
    float* __restrict__ out_act)
{
    const int b = blockIdx.x;
    const int t = threadIdx.x;

    __shared__ float v_lds[CO];                 // vsum[b] tile (640 B)
    __shared__ float coup_lds[NPOS * NC];       // 45 KB
    __shared__ float s_part[3 * 168];           // seg partials (+pad stride)

    if (t < CO) v_lds[t] = vsum[(size_t)b * CO + t];
    __syncthreads();

    // ---- pass 1: per-p logits + in-thread softmax -> coup_lds ----
    const int nk = (t < NPOS - 1024) ? 3 : 2;   // 1152 = 2*512 + 128
    for (int k = 0; k < nk; ++k) {
        const int p = t + 512 * k;
        const size_t pb16 = ((size_t)b * NC * NPOS + p) * 16;

        float lg[NC];
#pragma unroll
        for (int c = 0; c < NC; ++c) {
            const uint4* vp = (const uint4*)(votes + pb16 + (size_t)c * (NPOS * 16));
            const uint4 u0 = vp[0];
            const uint4 u1 = vp[1];
            const float* vl = v_lds + c * 16;
            float a = 0.f;
            a = fmaf(bflo(u0.x), vl[0],  a); a = fmaf(bfhi(u0.x), vl[1],  a);
            a = fmaf(bflo(u0.y), vl[2],  a); a = fmaf(bfhi(u0.y), vl[3],  a);
            a = fmaf(bflo(u0.z), vl[4],  a); a = fmaf(bfhi(u0.z), vl[5],  a);
            a = fmaf(bflo(u0.w), vl[6],  a); a = fmaf(bfhi(u0.w), vl[7],  a);
            a = fmaf(bflo(u1.x), vl[8],  a); a = fmaf(bfhi(u1.x), vl[9],  a);
            a = fmaf(bflo(u1.y), vl[10], a); a = fmaf(bfhi(u1.y), vl[11], a);
            a = fmaf(bflo(u1.z), vl[12], a); a = fmaf(bfhi(u1.z), vl[13], a);
            a = fmaf(bflo(u1.w), vl[14], a); a = fmaf(bfhi(u1.w), vl[15], a);
            lg[c] = a;
        }
        float mx = lg[0];
#pragma unroll
        for (int c = 1; c < NC; ++c) mx = fmaxf(mx, lg[c]);
        float coup[NC];
        float sum = 0.f;
#pragma unroll
        for (int c = 0; c < NC; ++c) { coup[c] = __expf(lg[c] - mx); sum += coup[c]; }
        const float inv = 1.f / sum;
#pragma unroll
        for (int c = 0; c < NC; ++c) {
            coup[c] *= inv;
            coup_lds[p * NC + c] = coup[c];
        }
        if (ITX == 2) {
            float* cp = out_coup + (size_t)b * (NC * NPOS) + p;
#pragma unroll
            for (int c = 0; c < NC; ++c) cp[(size_t)c * NPOS] = coup[c];
        }
    }
    __syncthreads();

    // ---- pass 2: s[c][o] = sum_p coup * votes (thread <-> (c,o,seg)) ----
    if (t < 480) {
        const int co  = t % 160;
        const int seg = t / 160;            // 0..2, 384 p each
        const int c = co >> 4, o = co & 15;
        const unsigned short* vp = votes + ((size_t)b * NC + c) * (NPOS * 16) + o;
        const float* cl = coup_lds + c;
        const int p0 = seg * 384;
        float a0 = 0.f, a1 = 0.f, a2 = 0.f, a3 = 0.f;
        for (int p = p0; p < p0 + 384; p += 8) {
            a0 = fmaf(cl[(p + 0) * NC], bfu(vp[(size_t)(p + 0) * 16]), a0);
            a1 = fmaf(cl[(p + 1) * NC], bfu(vp[(size_t)(p + 1) * 16]), a1);
            a2 = fmaf(cl[(p + 2) * NC], bfu(vp[(size_t)(p + 2) * 16]), a2);
            a3 = fmaf(cl[(p + 3) * NC], bfu(vp[(size_t)(p + 3) * 16]), a3);
            a0 = fmaf(cl[(p + 4) * NC], bfu(vp[(size_t)(p + 4) * 16]), a0);
            a1 = fmaf(cl[(p + 5) * NC], bfu(vp[(size_t)(p + 5) * 16]), a1);
            a2 = fmaf(cl[(p + 6) * NC], bfu(vp[(size_t)(p + 6) * 16]), a2);
            a3 = fmaf(cl[(p + 7) * NC], bfu(vp[(size_t)(p + 7) * 16]), a3);
        }
        s_part[seg * 168 + co] = ((a0 + a1) + (a2 + a3));
    }
    __syncthreads();

    // ---- tail: bias + squash, fused (t < 160) ----
    if (t < CO) {
        const int c = t >> 4;
        const float s = s_part[0 * 168 + t] + s_part[1 * 168 + t]
                      + s_part[2 * 168 + t] + rbias[t];
        float sq = s * s;
        sq += __shfl_xor(sq, 1);
        sq += __shfl_xor(sq, 2);
        sq += __shfl_xor(sq, 4);
        sq += __shfl_xor(sq, 8);
        const float f = (sq / (1.f + sq)) * rsqrtf(sq + CAPS_EPS);
        const float v = f * s;
        const size_t idx = (size_t)b * CO + t;
        if (ITX == 1) {
            vsum[idx] += v;                       // vsum = v0 + v1
        } else {
            out_poses[idx] = v;
            if ((t & 15) == 0) out_act[(size_t)b * NC + c] = sqrtf(f * f * sq + CAPS_EPS);
        }
    }
}

// ============ it0 squash (cross-slice reduction), unchanged/proven ==========
__global__ __launch_bounds__(256) void caps_squash_kernel(
    const float* __restrict__ rbias,
    float* __restrict__ sbuf,          // npart>0: part[npart][256][160]; else [256][160]
    float* __restrict__ vsum,
    float* __restrict__ out_poses,
    float* __restrict__ out_act,
    int it, int npart)
{
    const int b = blockIdx.x;
    const int t = threadIdx.x;
    if (t >= CO) return;
    const int c = t >> 4;

    const size_t idx = (size_t)b * CO + t;
    float s;
    if (npart > 0) {
        const float* p = sbuf + idx;
        const size_t stride = (size_t)NB * CO;
        float a0 = 0.f, a1 = 0.f, a2 = 0.f, a3 = 0.f;
        int px = 0;
        for (; px + 4 <= npart; px += 4) {
            a0 += p[(size_t)(px + 0) * stride];
            a1 += p[(size_t)(px + 1) * stride];
            a2 += p[(size_t)(px + 2) * stride];
            a3 += p[(size_t)(px + 3) * stride];
        }
        for (; px < npart; ++px) a0 += p[(size_t)px * stride];
        s = ((a0 + a1) + (a2 + a3)) + rbias[t];
    } else {
        s = sbuf[idx] + rbias[t];
    }

    float sq = s * s;
    sq += __shfl_xor(sq, 1);
    sq += __shfl_xor(sq, 2);
    sq += __shfl_xor(sq, 4);
    sq += __shfl_xor(sq, 8);
    const float f = (sq / (1.f + sq)) * rsqrtf(sq + CAPS_EPS);
    const float v = f * s;

    if (it < 2) {
        vsum[idx] += v;
        if (npart == 0) sbuf[idx] = 0.f;
    } else {
        out_poses[idx] = v;
        if ((t & 15) == 0) out_act[(size_t)b * NC + c] = sqrtf(f * f * sq + CAPS_EPS);
    }
}

// ============ legacy small-ws fallback (raw-read, atomic merge) =============
__global__ __launch_bounds__(256) void caps_votes_fb(
    const float* __restrict__ poses, const float* __restrict__ weight,
    const float* __restrict__ vsum, float* __restrict__ sbuf,
    float* __restrict__ out_coup, int it)
{
    const int t = threadIdx.x, wave = t >> 6, lane = t & 63;
    const int bcol = lane & 15, quad = lane >> 4;
    const int bt = blockIdx.y, b0 = bt * 16;
    const int pbase = blockIdx.x * PPB + wave * PW;

    __shared__ float s_lds[16 * 161];
    for (int k = t; k < 16 * 161; k += 256) s_lds[k] = 0.f;

    float4 vs[NC];
    if (it > 0) {
        const float* vp = vsum + (size_t)(b0 + bcol) * CO + quad * 4;
#pragma unroll
        for (int c = 0; c < NC; ++c) vs[c] = *(const float4*)(vp + c * 16);
    }
    __syncthreads();

    floatx4 sacc[NC];
#pragma unroll
    for (int c = 0; c < NC; ++c) sacc[c] = (floatx4)(0.f);

    for (int pi = 0; pi < PW; ++pi) {
        const int p = pbase + pi;
        const uint2 bfrag = pack4(*(const float4*)(poses +
            ((size_t)(b0 + bcol) * NPOS + p) * IS + quad * 4));
        floatx4 acc[NC];
#pragma unroll
        for (int c = 0; c < NC; ++c) {
            const uint2 a = pack4(*(const float4*)(weight +
                (size_t)(p * NC + c) * 256 + bcol * 16 + quad * 4));
            acc[c] = MFMA16(a, bfrag, (floatx4)(0.f));
        }
        if (it == 0) {
#pragma unroll
            for (int c = 0; c < NC; ++c)
#pragma unroll
                for (int r = 0; r < 4; ++r) sacc[c][r] += acc[c][r];
        } else {
            float lg[NC], mx = -1e30f;
#pragma unroll
            for (int c = 0; c < NC; ++c) {
                float pt = vs[c].x * acc[c][0] + vs[c].y * acc[c][1]
                         + vs[c].z * acc[c][2] + vs[c].w * acc[c][3];
                pt += __shfl_xor(pt, 16);
                pt += __shfl_xor(pt, 32);
                lg[c] = pt; mx = fmaxf(mx, pt);
            }
            float coup[NC], sum = 0.f;
#pragma unroll
            for (int c = 0; c < NC; ++c) { coup[c] = __expf(lg[c] - mx); sum += coup[c]; }
            const float inv = 1.f / sum;
#pragma unroll
            for (int c = 0; c < NC; ++c) coup[c] *= inv;
            if (it == 2 && quad == 0) {
                float* cp = out_coup + (size_t)(b0 + bcol) * (NC * NPOS) + p;
#pragma unroll
                for (int c = 0; c < NC; ++c) cp[c * NPOS] = coup[c];
            }
#pragma unroll
            for (int c = 0; c < NC; ++c)
#pragma unroll
                for (int r = 0; r < 4; ++r) sacc[c][r] += coup[c] * acc[c][r];
        }
    }

    const float scale = (it == 0) ? 0.1f : 1.f;
#pragma unroll
    for (int c = 0; c < NC; ++c)
#pragma unroll
        for (int r = 0; r < 4; ++r)
            atomicAdd(&s_lds[bcol * 161 + c * 16 + quad * 4 + r], scale * sacc[c][r]);
    __syncthreads();
    for (int k = t; k < 16 * CO; k += 256) {
        const int b = k / CO, jj = k - b * CO;
        unsafeAtomicAdd(&sbuf[(size_t)(b0 + b) * CO + jj], s_lds[b * 161 + jj]);
    }
}

extern "C" void kernel_launch(void* const* d_in, const int* in_sizes, int n_in,
                              void* d_out, int out_size, void* d_ws, size_t ws_size,
                              hipStream_t stream) {
    const float* poses  = (const float*)d_in[0];
    // d_in[1] (input_caps_activations) unused by the reference computation.
    const float* weight = (const float*)d_in[2];
    const float* rbias  = (const float*)d_in[3];

    float* out       = (float*)d_out;
    float* out_poses = out;                                   // 256*10*16
    float* out_act   = out + (size_t)NB * CO;                 // 256*10
    float* out_coup  = out_act + (size_t)NB * NC;             // 256*10*1152

    const size_t part_bytes  = (size_t)PBLK * NB * CO * sizeof(float);       // 7.86 MB
    const size_t vsum_bytes  = (size_t)NB * CO * sizeof(float);              // 160 KB
    const size_t votes_bytes = (size_t)NB * NC * NPOS * 16 * sizeof(unsigned short); // 94.4 MB
    const size_t need_full   = part_bytes + vsum_bytes + votes_bytes;        // 102.4 MB

    if (ws_size >= need_full) {
        float* part = (float*)d_ws;
        float* vsum = part + (size_t)PBLK * NB * CO;
        unsigned short* votes = (unsigned short*)((char*)d_ws + part_bytes + vsum_bytes);

        (void)hipMemsetAsync(vsum, 0, vsum_bytes, stream);

        hipLaunchKernelGGL(caps_mat, dim3(PBLK * 16), dim3(256), 0, stream,
                           poses, weight, votes, part);
        hipLaunchKernelGGL(caps_squash_kernel, dim3(NB), dim3(256), 0, stream,
                           rbias, part, vsum, out_poses, out_act, 0, PBLK);
        hipLaunchKernelGGL((caps_route<1>), dim3(NB), dim3(512), 0, stream,
                           votes, rbias, vsum, out_coup, out_poses, out_act);
        hipLaunchKernelGGL((caps_route<2>), dim3(NB), dim3(512), 0, stream,
                           votes, rbias, vsum, out_coup, out_poses, out_act);
    } else {
        // legacy small-ws path: raw-read MFMA + atomic accumulator
        float* sbuf = (float*)d_ws;
        float* vsum = sbuf + (size_t)NB * CO;
        (void)hipMemsetAsync(d_ws, 0, 2 * vsum_bytes, stream);
        for (int it = 0; it < 3; ++it) {
            hipLaunchKernelGGL(caps_votes_fb, dim3(PBLK, 16), dim3(256), 0, stream,
                               poses, weight, vsum, sbuf, out_coup, it);
            hipLaunchKernelGGL(caps_squash_kernel, dim3(NB), dim3(256), 0, stream,
                               rbias, sbuf, vsum, out_poses, out_act, it, 0);
        }
    }
}